// Round 14
// baseline (233.181 us; speedup 1.0000x reference)
//
#include <hip/hip_runtime.h>
#include <hip/hip_bf16.h>
#include <cmath>

#define B_   4
#define NT_  2048
#define G_   4096
#define DZ_  128

typedef __attribute__((ext_vector_type(8))) short bf16x8;
typedef __attribute__((ext_vector_type(8))) short s16x8;
typedef __attribute__((ext_vector_type(4))) float f32x4;

__device__ __forceinline__ float softplus_f(float x) {
    return fmaxf(x, 0.0f) + log1pf(expf(-fabsf(x)));
}

// async 16B global -> LDS (lane i lands at ldst + 16*i; ldst wave-uniform)
__device__ __forceinline__ void gl2lds16(const void* gsrc, void* ldst) {
    __builtin_amdgcn_global_load_lds(
        (const __attribute__((address_space(1))) unsigned int*)gsrc,
        (__attribute__((address_space(3))) unsigned int*)ldst, 16, 0, 0);
}

// z_grid (B,G,DZ) fp32 -> Zt3 FRAG-MAJOR bf16 tiles (v9 layout, verified 2x):
//   Zt3[ ((b*128 + c)*8 + nt)*512 + (q*16 + l15)*8 + j ]
// MFMA B-frag ds_read_b128 at mytile + nt*512 + lane*8 = conflict-free.
__global__ __launch_bounds__(256, 1)
void transpose_z(const float* __restrict__ z, unsigned short* __restrict__ zt)
{
    __shared__ unsigned short tile[64][66];
    const int bx = blockIdx.x;                // 4b * 64gt * 2zt = 512
    const int zti = bx & 1;
    const int gt  = (bx >> 1) & 63;
    const int b   = bx >> 7;
    const int g0 = gt * 64, z0 = zti * 64;
    const int tid = threadIdx.x;
    const int zl = tid & 63, gl = tid >> 6;
    #pragma unroll
    for (int i = 0; i < 16; ++i) {
        const int g = gl + i * 4;
        const float v = z[(size_t)(b * G_ + g0 + g) * DZ_ + z0 + zl];
        unsigned int u = __float_as_uint(v);
        u = u + 0x7FFFu + ((u >> 16) & 1u);   // RNE to bf16
        tile[g][zl] = (unsigned short)(u >> 16);
    }
    __syncthreads();
    const int nt  = tid >> 6;                 // frag (z-block) 0..3 (local)
    const int q   = (tid >> 4) & 3;           // g-octet within chunk
    const int fl  = tid & 15;                 // l15 (z within frag)
    #pragma unroll
    for (int i = 0; i < 2; ++i) {             // chunk-local (c = gt*2 + i)
        s16x8 v;
        #pragma unroll
        for (int j = 0; j < 8; ++j)
            v[j] = (short)tile[i * 32 + q * 8 + j][nt * 16 + fl];
        *(s16x8*)(zt + ((size_t)(b * 128 + gt * 2 + i) * 8 + zti * 4 + nt) * 512
                  + (size_t)(q * 16 + fl) * 8) = v;
    }
}

// v14: Tt=32 PER WAVE (halves the per-CU VMEM pole, the invariant ~14 us in
// every 38-48 us variant).  256 blocks x 8 waves (kh g-split, 16 chunks);
// each wave computes BOTH 16-row t-sets from ONE staged tile (4 MFMA/frag).
// The v2 spill is now understood (AGPR/arch split of the unified file:
// 128 AGPR acc leaves arch = budget-128) and avoided: launch_bounds(512,2)
// -> 256 unified/wave -> ~128 arch available; jg-grouped weights keep arch
// need ~75.  v9 frag-major Zt (conflict-free), v10 split counted drain.
// LDS 128 KB: first 64 KB = 8 private wave slots; full 128 KB = reduction.
__global__ __launch_bounds__(512, 2)
void setconv_main(const float* __restrict__ xt,
                  const float* __restrict__ xg,
                  const float* __restrict__ lsp,
                  const unsigned short* __restrict__ Zt,
                  float* __restrict__ out)
{
    __shared__ __align__(16) unsigned short lds[65536];  // 128 KB

    // XCD swizzle: 256 blocks; same-b blocks land on 2 XCDs
    const int bx = blockIdx.x;
    const int b  = (bx >> 1) & 3;
    const int tt = ((bx >> 3) << 1) | (bx & 1);   // 0..63
    const int tid  = threadIdx.x;
    const int w    = tid >> 6;                // = kh, 0..7
    const int lane = tid & 63;
    const int quad = lane >> 4;
    const int l15  = lane & 15;
    const int t0   = tt * 32;

    float c00, c01, c10, c11;
    {
        const float h = -0.72134752f;         // -0.5*log2(e)
        float ls;
        ls = 1e-5f + softplus_f(lsp[0]); c00 = h / (ls * ls);
        ls = 1e-5f + softplus_f(lsp[1]); c01 = h / (ls * ls);
        ls = 1e-5f + softplus_f(lsp[2]); c10 = h / (ls * ls);
        ls = 1e-5f + softplus_f(lsp[3]); c11 = h / (ls * ls);
    }

    // two A-frag row sets: rows t0+l15 (ts 0) and t0+16+l15 (ts 1)
    const float xtA0 = xt[(size_t)(b * NT_ + t0 + l15) * 2 + 0];
    const float xtA1 = xt[(size_t)(b * NT_ + t0 + l15) * 2 + 1];
    const float xtB0 = xt[(size_t)(b * NT_ + t0 + 16 + l15) * 2 + 0];
    const float xtB1 = xt[(size_t)(b * NT_ + t0 + 16 + l15) * 2 + 1];

    f32x4 acc[2][2][8];                       // [ts][k][nt] = 128 AGPR
    #pragma unroll
    for (int ts = 0; ts < 2; ++ts)
        #pragma unroll
        for (int k = 0; k < 2; ++k)
            #pragma unroll
            for (int n = 0; n < 8; ++n) acc[ts][k][n] = (f32x4)0.0f;

    unsigned short* const mytile = lds + w * 4096;       // private 8 KB slot
    const float* xgq = xg + (size_t)(b * G_ + w * 512 + quad * 8) * 2;
    const unsigned short* zs0 = Zt + (size_t)(b * 128 + w * 16) * 4096 + lane * 8;

    // prologue: xv(0) first (oldest), then stage(0) all 8 frags
    float4 xv0 = *(const float4*)(xgq + 0);
    float4 xv1 = *(const float4*)(xgq + 4);
    float4 xv2 = *(const float4*)(xgq + 8);
    float4 xv3 = *(const float4*)(xgq + 12);
    #pragma unroll
    for (int i = 0; i < 8; ++i)
        gl2lds16(zs0 + i * 512, mytile + i * 512);

    #pragma unroll
    for (int ch = 0; ch < 16; ++ch) {
        // ---- weights(ch), jg-grouped: live transient stays ~16 regs ----
        union { bf16x8 v; unsigned int u[4]; } aA0, aA1, aB0, aB1;
        #pragma unroll
        for (int jg = 0; jg < 2; ++jg) {
            const float4 xa = jg ? xv2 : xv0;
            const float4 xb = jg ? xv3 : xv1;
            const float px[4] = {xa.x, xa.z, xb.x, xb.z};
            const float py[4] = {xa.y, xa.w, xb.y, xb.w};
            {
                unsigned int w0b[4], w1b[4];
                #pragma unroll
                for (int j = 0; j < 4; ++j) {
                    const float d0 = xtA0 - px[j];
                    const float d1 = xtA1 - py[j];
                    const float q0 = d0 * d0;
                    const float q1 = d1 * d1;
                    const float e0 = fmaf(q1, c10, q0 * c00);
                    const float e1 = fmaf(q1, c11, q0 * c01);
                    w0b[j] = __float_as_uint(__builtin_amdgcn_exp2f(e0));
                    w1b[j] = __float_as_uint(__builtin_amdgcn_exp2f(e1));
                }
                aA0.u[jg * 2 + 0] = __builtin_amdgcn_perm(w0b[1], w0b[0], 0x07060302u);
                aA0.u[jg * 2 + 1] = __builtin_amdgcn_perm(w0b[3], w0b[2], 0x07060302u);
                aA1.u[jg * 2 + 0] = __builtin_amdgcn_perm(w1b[1], w1b[0], 0x07060302u);
                aA1.u[jg * 2 + 1] = __builtin_amdgcn_perm(w1b[3], w1b[2], 0x07060302u);
            }
            {
                unsigned int w0b[4], w1b[4];
                #pragma unroll
                for (int j = 0; j < 4; ++j) {
                    const float d0 = xtB0 - px[j];
                    const float d1 = xtB1 - py[j];
                    const float q0 = d0 * d0;
                    const float q1 = d1 * d1;
                    const float e0 = fmaf(q1, c10, q0 * c00);
                    const float e1 = fmaf(q1, c11, q0 * c01);
                    w0b[j] = __float_as_uint(__builtin_amdgcn_exp2f(e0));
                    w1b[j] = __float_as_uint(__builtin_amdgcn_exp2f(e1));
                }
                aB0.u[jg * 2 + 0] = __builtin_amdgcn_perm(w0b[1], w0b[0], 0x07060302u);
                aB0.u[jg * 2 + 1] = __builtin_amdgcn_perm(w0b[3], w0b[2], 0x07060302u);
                aB1.u[jg * 2 + 0] = __builtin_amdgcn_perm(w1b[1], w1b[0], 0x07060302u);
                aB1.u[jg * 2 + 1] = __builtin_amdgcn_perm(w1b[3], w1b[2], 0x07060302u);
            }
        }

        // ---- first-half drain: S(ch) frags 0-3 ----
        __builtin_amdgcn_s_waitcnt(0x0F74);          // vmcnt(4)
        __builtin_amdgcn_s_setprio(1);
        #pragma unroll
        for (int nt = 0; nt < 4; ++nt) {
            const bf16x8 bz = *(const bf16x8*)(mytile + nt * 512 + lane * 8);
            acc[0][0][nt] = __builtin_amdgcn_mfma_f32_16x16x32_bf16(aA0.v, bz, acc[0][0][nt], 0, 0, 0);
            acc[0][1][nt] = __builtin_amdgcn_mfma_f32_16x16x32_bf16(aA1.v, bz, acc[0][1][nt], 0, 0, 0);
            acc[1][0][nt] = __builtin_amdgcn_mfma_f32_16x16x32_bf16(aB0.v, bz, acc[1][0][nt], 0, 0, 0);
            acc[1][1][nt] = __builtin_amdgcn_mfma_f32_16x16x32_bf16(aB1.v, bz, acc[1][1][nt], 0, 0, 0);
        }
        __builtin_amdgcn_s_setprio(0);

        // ---- xv(ch+1) + stage(ch+1) frags 0-3 into the consumed half ----
        if (ch < 15) {
            const float* xp = xgq + (ch + 1) * 64;
            xv0 = *(const float4*)(xp + 0);
            xv1 = *(const float4*)(xp + 4);
            xv2 = *(const float4*)(xp + 8);
            xv3 = *(const float4*)(xp + 12);
            const unsigned short* zs = zs0 + (size_t)(ch + 1) * 4096;
            #pragma unroll
            for (int i = 0; i < 4; ++i)
                gl2lds16(zs + i * 512, mytile + i * 512);
        }

        // ---- second-half drain: retires exactly S(ch) frags 4-7 ----
        if (ch < 15)
            __builtin_amdgcn_s_waitcnt(0x0F78);      // vmcnt(8): [X',S'0-3] stay
        else
            __builtin_amdgcn_s_waitcnt(0x0F70);      // tail: vmcnt(0)
        __builtin_amdgcn_s_setprio(1);
        #pragma unroll
        for (int nt = 4; nt < 8; ++nt) {
            const bf16x8 bz = *(const bf16x8*)(mytile + nt * 512 + lane * 8);
            acc[0][0][nt] = __builtin_amdgcn_mfma_f32_16x16x32_bf16(aA0.v, bz, acc[0][0][nt], 0, 0, 0);
            acc[0][1][nt] = __builtin_amdgcn_mfma_f32_16x16x32_bf16(aA1.v, bz, acc[0][1][nt], 0, 0, 0);
            acc[1][0][nt] = __builtin_amdgcn_mfma_f32_16x16x32_bf16(aB0.v, bz, acc[1][0][nt], 0, 0, 0);
            acc[1][1][nt] = __builtin_amdgcn_mfma_f32_16x16x32_bf16(aB1.v, bz, acc[1][1][nt], 0, 0, 0);
        }
        __builtin_amdgcn_s_setprio(0);

        // ---- stage(ch+1) frags 4-7 ----
        if (ch < 15) {
            const unsigned short* zs = zs0 + (size_t)(ch + 1) * 4096;
            #pragma unroll
            for (int i = 4; i < 8; ++i)
                gl2lds16(zs + i * 512, mytile + i * 512);
        }
    }

    // ---- 3-round k-reduction over 8 waves (v2's verified version) ----
    float* const red = (float*)lds;           // slot s: 32 KB at s*8192 floats
    #define RED_W(slot) { \
        float* bp = &red[(slot) * 8192 + lane * 4]; \
        _Pragma("unroll") \
        for (int ts = 0; ts < 2; ++ts) \
            _Pragma("unroll") \
            for (int k = 0; k < 2; ++k) \
                _Pragma("unroll") \
                for (int n = 0; n < 8; ++n) \
                    *(f32x4*)(bp + (ts * 16 + k * 8 + n) * 256) = acc[ts][k][n]; }
    #define RED_A(slot) { \
        const float* bp = &red[(slot) * 8192 + lane * 4]; \
        _Pragma("unroll") \
        for (int ts = 0; ts < 2; ++ts) \
            _Pragma("unroll") \
            for (int k = 0; k < 2; ++k) \
                _Pragma("unroll") \
                for (int n = 0; n < 8; ++n) \
                    acc[ts][k][n] += *(const f32x4*)(bp + (ts * 16 + k * 8 + n) * 256); }
    #define RED_W_T(slot, ts) { \
        float* bp = &red[(slot) * 8192 + lane * 4]; \
        _Pragma("unroll") \
        for (int k = 0; k < 2; ++k) \
            _Pragma("unroll") \
            for (int n = 0; n < 8; ++n) \
                *(f32x4*)(bp + (k * 8 + n) * 256) = acc[ts][k][n]; }
    #define RED_A_T(slot, ts) { \
        const float* bp = &red[(slot) * 8192 + lane * 4]; \
        _Pragma("unroll") \
        for (int k = 0; k < 2; ++k) \
            _Pragma("unroll") \
            for (int n = 0; n < 8; ++n) \
                acc[ts][k][n] += *(const f32x4*)(bp + (k * 8 + n) * 256); }

    __syncthreads();
    if (w >= 4) RED_W(w - 4);
    __syncthreads();
    if (w < 4) RED_A(w);
    if (w == 2 || w == 3) RED_W(w);
    __syncthreads();
    if (w < 2) RED_A(w + 2);
    if (w == 1) RED_W_T(3, 0);
    if (w == 0) RED_W_T(2, 1);
    __syncthreads();
    if (w < 2) {
        if (w == 0) { RED_A_T(3, 0); } else { RED_A_T(2, 1); }
        const int ts = w;
        const int tr = t0 + ts * 16 + quad * 4;
        #pragma unroll
        for (int nt = 0; nt < 8; ++nt) {
            float* ob = out + (size_t)(b * NT_ + tr) * (DZ_ * 2) + (nt * 16 + l15) * 2;
            #pragma unroll
            for (int r = 0; r < 4; ++r)
                *(float2*)(ob + (size_t)r * (DZ_ * 2)) =
                    make_float2(acc[ts][0][nt][r], acc[ts][1][nt][r]);
        }
    }
    #undef RED_W
    #undef RED_A
    #undef RED_W_T
    #undef RED_A_T
}

extern "C" void kernel_launch(void* const* d_in, const int* in_sizes, int n_in,
                              void* d_out, int out_size, void* d_ws, size_t ws_size,
                              hipStream_t stream)
{
    const float* x_grid = (const float*)d_in[0];   // (4,64,64,2)
    const float* z_grid = (const float*)d_in[1];   // (4,64,64,128)
    const float* xt     = (const float*)d_in[2];   // (4,2048,2)
    const float* lsp    = (const float*)d_in[3];   // (2,2)
    float* out = (float*)d_out;                    // (4,2048,256) fp32
    unsigned short* Zt = (unsigned short*)d_ws;    // tiled, 4 MB

    hipLaunchKernelGGL(transpose_z, dim3(512), dim3(256), 0, stream, z_grid, Zt);
    hipLaunchKernelGGL(setconv_main, dim3(256), dim3(512), 0, stream,
                       xt, x_grid, lsp, Zt, out);
}

// Round 16
// 106.295 us; speedup vs baseline: 2.1937x; 2.1937x over previous
//
#include <hip/hip_runtime.h>
#include <hip/hip_bf16.h>
#include <cmath>

#define B_   4
#define NT_  2048
#define G_   4096
#define DZ_  128

typedef __attribute__((ext_vector_type(8))) short bf16x8;
typedef __attribute__((ext_vector_type(8))) short s16x8;
typedef __attribute__((ext_vector_type(4))) float f32x4;

__device__ __forceinline__ float softplus_f(float x) {
    return fmaxf(x, 0.0f) + log1pf(expf(-fabsf(x)));
}

// async 16B global -> LDS (lane i lands at ldst + 16*i; ldst wave-uniform)
__device__ __forceinline__ void gl2lds16(const void* gsrc, void* ldst) {
    __builtin_amdgcn_global_load_lds(
        (const __attribute__((address_space(1))) unsigned int*)gsrc,
        (__attribute__((address_space(3))) unsigned int*)ldst, 16, 0, 0);
}

// z_grid (B,G,DZ) fp32 -> Zt3 FRAG-MAJOR bf16 tiles (v9 layout, 4x verified):
//   Zt3[ ((b*128 + c)*8 + nt)*512 + (q*16 + l15)*8 + j ]
// B-frag = contiguous 1 KB, lane-contiguous 16 B/lane -> conflict-free reads.
__global__ __launch_bounds__(256, 1)
void transpose_z(const float* __restrict__ z, unsigned short* __restrict__ zt)
{
    __shared__ unsigned short tile[64][66];
    const int bx = blockIdx.x;                // 4b * 64gt * 2zt = 512
    const int zti = bx & 1;
    const int gt  = (bx >> 1) & 63;
    const int b   = bx >> 7;
    const int g0 = gt * 64, z0 = zti * 64;
    const int tid = threadIdx.x;
    const int zl = tid & 63, gl = tid >> 6;
    #pragma unroll
    for (int i = 0; i < 16; ++i) {
        const int g = gl + i * 4;
        const float v = z[(size_t)(b * G_ + g0 + g) * DZ_ + z0 + zl];
        unsigned int u = __float_as_uint(v);
        u = u + 0x7FFFu + ((u >> 16) & 1u);   // RNE to bf16
        tile[g][zl] = (unsigned short)(u >> 16);
    }
    __syncthreads();
    const int nt  = tid >> 6;                 // frag (z-block) 0..3 (local)
    const int q   = (tid >> 4) & 3;           // g-octet within chunk
    const int fl  = tid & 15;                 // l15 (z within frag)
    #pragma unroll
    for (int i = 0; i < 2; ++i) {             // chunk-local (c = gt*2 + i)
        s16x8 v;
        #pragma unroll
        for (int j = 0; j < 8; ++j)
            v[j] = (short)tile[i * 32 + q * 8 + j][nt * 16 + fl];
        *(s16x8*)(zt + ((size_t)(b * 128 + gt * 2 + i) * 8 + zti * 4 + nt) * 512
                  + (size_t)(q * 16 + fl) * 8) = v;
    }
}

// v15: Tt=32 PER BLOCK via ts-pair SHARED tiles (v4 structure + all fixes).
// 256 blocks (1/CU) x 8 waves = 2ts x 4p.  Pair (p) shares a double-buffered
// 2 x 8 KB slot; each wave stages its own 4 frags (ts*4..ts*4+3); both waves
// consume all 8.  ONE barrier per chunk: the barrier at top of chunk ch also
// proves both waves finished READING slot[(ch+1)&1] (read in iter ch-1), so
// stage(ch+1) issues right after it.  Weights software-pipelined (W(ch+1)
// computed at end of iter ch -> implicit xv wait = vmcnt(4), S stays in
// flight a full chunk).  acc 64 AGPR + ~70 arch = no spill (the 128-acc
// Tt=32-per-wave variant spilled under BOTH launch-bound settings).
// Frag-major Zt -> conflict-free ds_read; per-CU: LDS wr 1 MB rd 2 MB,
// L1/L2 stream 1 MB (halved vs v9's 2 MB), VALU ~8 us, MFMA ~8 us.
__global__ __launch_bounds__(512, 2)
void setconv_main(const float* __restrict__ xt,
                  const float* __restrict__ xg,
                  const float* __restrict__ lsp,
                  const unsigned short* __restrict__ Zt,
                  float* __restrict__ out)
{
    __shared__ __align__(16) unsigned short lds[32768];  // 64 KB: 4p x 2 x 8 KB

    // XCD swizzle: 256 blocks; same-b blocks land on 2 XCDs
    const int bx = blockIdx.x;
    const int b  = (bx >> 1) & 3;
    const int tt = ((bx >> 3) << 1) | (bx & 1);   // 0..63
    const int tid  = threadIdx.x;
    const int w    = tid >> 6;
    const int ts   = w >> 2;                  // t-set 0/1
    const int p    = w & 3;                   // g-group 0..3
    const int lane = tid & 63;
    const int quad = lane >> 4;
    const int l15  = lane & 15;
    const int t0   = tt * 32;

    float c00, c01, c10, c11;
    {
        const float h = -0.72134752f;         // -0.5*log2(e)
        float ls;
        ls = 1e-5f + softplus_f(lsp[0]); c00 = h / (ls * ls);
        ls = 1e-5f + softplus_f(lsp[1]); c01 = h / (ls * ls);
        ls = 1e-5f + softplus_f(lsp[2]); c10 = h / (ls * ls);
        ls = 1e-5f + softplus_f(lsp[3]); c11 = h / (ls * ls);
    }

    // this wave's 16 t-rows
    const float xt0 = xt[(size_t)(b * NT_ + t0 + ts * 16 + l15) * 2 + 0];
    const float xt1 = xt[(size_t)(b * NT_ + t0 + ts * 16 + l15) * 2 + 1];

    f32x4 acc[2][8];                          // [k][nt] = 64 AGPR
    #pragma unroll
    for (int k = 0; k < 2; ++k)
        #pragma unroll
        for (int n = 0; n < 8; ++n) acc[k][n] = (f32x4)0.0f;

    unsigned short* const slot0 = lds + p * 8192;   // pair-shared 2 x 8 KB
    unsigned short* const slot1 = slot0 + 4096;
    const float* xgq = xg + (size_t)(b * G_ + p * 1024 + quad * 8) * 2;
    // chunk ch tile at zs0 + ch*4096 shorts; frag nt at +nt*512, lane*8 within
    const unsigned short* zs0 = Zt + (size_t)(b * 128 + p * 32) * 4096 + lane * 8;

    // my staging half: frags ts*4 .. ts*4+3
    #define STAGE(C, SLOT) {                                                   \
        const unsigned short* zc = zs0 + (size_t)(C) * 4096;                   \
        _Pragma("unroll")                                                      \
        for (int i = 0; i < 4; ++i)                                            \
            gl2lds16(zc + (ts * 4 + i) * 512, (SLOT) + (ts * 4 + i) * 512);    \
    }

    // weights for chunk CH from xv regs -> aC0/aC1 (jg-grouped, ~16 transient)
    union bfu { bf16x8 v; unsigned int u[4]; };
    bfu aC0, aC1;
    #define WEIGHTS() {                                                        \
        _Pragma("unroll")                                                      \
        for (int jg = 0; jg < 2; ++jg) {                                       \
            const float4 xa = jg ? xv2 : xv0;                                  \
            const float4 xb = jg ? xv3 : xv1;                                  \
            const float px[4] = {xa.x, xa.z, xb.x, xb.z};                      \
            const float py[4] = {xa.y, xa.w, xb.y, xb.w};                      \
            unsigned int w0b[4], w1b[4];                                       \
            _Pragma("unroll")                                                  \
            for (int j = 0; j < 4; ++j) {                                      \
                const float d0 = xt0 - px[j];                                  \
                const float d1 = xt1 - py[j];                                  \
                const float q0 = d0 * d0;                                      \
                const float q1 = d1 * d1;                                      \
                const float e0 = fmaf(q1, c10, q0 * c00);                      \
                const float e1 = fmaf(q1, c11, q0 * c01);                      \
                w0b[j] = __float_as_uint(__builtin_amdgcn_exp2f(e0));          \
                w1b[j] = __float_as_uint(__builtin_amdgcn_exp2f(e1));          \
            }                                                                  \
            aC0.u[jg * 2 + 0] = __builtin_amdgcn_perm(w0b[1], w0b[0], 0x07060302u); \
            aC0.u[jg * 2 + 1] = __builtin_amdgcn_perm(w0b[3], w0b[2], 0x07060302u); \
            aC1.u[jg * 2 + 0] = __builtin_amdgcn_perm(w1b[1], w1b[0], 0x07060302u); \
            aC1.u[jg * 2 + 1] = __builtin_amdgcn_perm(w1b[3], w1b[2], 0x07060302u); \
        }                                                                      \
    }

    // prologue: xv(0) (oldest), stage(0)->slot0, W(0) (waits xv only: vmcnt(4))
    float4 xv0 = *(const float4*)(xgq + 0);
    float4 xv1 = *(const float4*)(xgq + 4);
    float4 xv2 = *(const float4*)(xgq + 8);
    float4 xv3 = *(const float4*)(xgq + 12);
    STAGE(0, slot0);
    WEIGHTS();

    for (int ch = 0; ch < 32; ++ch) {
        // S(ch) fully landed (issued a full chunk ago), then block-wide sync:
        // partner's S(ch) half visible; partner's reads of slot[(ch+1)&1]
        // (done in iter ch-1) complete -> safe to restage it.
        __builtin_amdgcn_s_waitcnt(0x0F70);          // vmcnt(0)
        __builtin_amdgcn_s_barrier();

        if (ch < 31) {
            const float* xp = xgq + (ch + 1) * 64;
            xv0 = *(const float4*)(xp + 0);
            xv1 = *(const float4*)(xp + 4);
            xv2 = *(const float4*)(xp + 8);
            xv3 = *(const float4*)(xp + 12);
            unsigned short* dst = ((ch + 1) & 1) ? slot1 : slot0;
            STAGE(ch + 1, dst);
        }

        // consume tile(ch) with W(ch) (computed last iter / prologue)
        const unsigned short* tile = (ch & 1) ? slot1 : slot0;
        __builtin_amdgcn_s_setprio(1);
        #pragma unroll
        for (int nt = 0; nt < 8; ++nt) {
            const bf16x8 bz = *(const bf16x8*)(tile + nt * 512 + lane * 8);
            acc[0][nt] = __builtin_amdgcn_mfma_f32_16x16x32_bf16(aC0.v, bz, acc[0][nt], 0, 0, 0);
            acc[1][nt] = __builtin_amdgcn_mfma_f32_16x16x32_bf16(aC1.v, bz, acc[1][nt], 0, 0, 0);
        }
        __builtin_amdgcn_s_setprio(0);

        // W(ch+1): implicit xv wait = vmcnt(4) -> S(ch+1) stays in flight
        if (ch < 31) WEIGHTS();
    }
    #undef WEIGHTS
    #undef STAGE

    // ---- 2-round p-reduction per t-set (v4's verified version) ----
    float* const red = (float*)lds;           // slot s: 16 KB at s*4096 floats
    #define RED_W(slot) { \
        float* bp = &red[(slot) * 4096 + lane * 4]; \
        _Pragma("unroll") \
        for (int k = 0; k < 2; ++k) \
            _Pragma("unroll") \
            for (int n = 0; n < 8; ++n) \
                *(f32x4*)(bp + (k * 8 + n) * 256) = acc[k][n]; }
    #define RED_A(slot) { \
        const float* bp = &red[(slot) * 4096 + lane * 4]; \
        _Pragma("unroll") \
        for (int k = 0; k < 2; ++k) \
            _Pragma("unroll") \
            for (int n = 0; n < 8; ++n) \
                acc[k][n] += *(const f32x4*)(bp + (k * 8 + n) * 256); }

    __syncthreads();                          // main loop done (all waves)
    if (p >= 2) RED_W(ts * 2 + (p - 2));      // ts0:{p2->0,p3->1} ts1:{p2->2,p3->3}
    __syncthreads();
    if (p < 2) RED_A(ts * 2 + p);             // p0+=slot(ts*2), p1+=slot(ts*2+1)
    __syncthreads();                          // protect slot overwrite
    if (p == 1) RED_W(ts);                    // ts0p1->slot0, ts1p1->slot1
    __syncthreads();
    if (p == 0) {
        RED_A(ts);
        const int tr = t0 + ts * 16 + quad * 4;
        #pragma unroll
        for (int nt = 0; nt < 8; ++nt) {
            float* ob = out + (size_t)(b * NT_ + tr) * (DZ_ * 2) + (nt * 16 + l15) * 2;
            #pragma unroll
            for (int r = 0; r < 4; ++r)
                *(float2*)(ob + (size_t)r * (DZ_ * 2)) =
                    make_float2(acc[0][nt][r], acc[1][nt][r]);
        }
    }
    #undef RED_W
    #undef RED_A
}

extern "C" void kernel_launch(void* const* d_in, const int* in_sizes, int n_in,
                              void* d_out, int out_size, void* d_ws, size_t ws_size,
                              hipStream_t stream)
{
    const float* x_grid = (const float*)d_in[0];   // (4,64,64,2)
    const float* z_grid = (const float*)d_in[1];   // (4,64,64,128)
    const float* xt     = (const float*)d_in[2];   // (4,2048,2)
    const float* lsp    = (const float*)d_in[3];   // (2,2)
    float* out = (float*)d_out;                    // (4,2048,256) fp32
    unsigned short* Zt = (unsigned short*)d_ws;    // tiled, 4 MB

    hipLaunchKernelGGL(transpose_z, dim3(512), dim3(256), 0, stream, z_grid, Zt);
    hipLaunchKernelGGL(setconv_main, dim3(256), dim3(512), 0, stream,
                       xt, x_grid, lsp, Zt, out);
}